// Round 8
// baseline (365.562 us; speedup 1.0000x reference)
//
#include <hip/hip_runtime.h>
#include <hip/hip_bf16.h>

// Problem constants (from reference)
#define BATCH 16384
#define DIM   128
#define HID   1024
#define NK    8
#define OPD   25          // 3*K+1
#define N3    (DIM*OPD)   // 3200
#define NP    3328        // 26 tiles x 128 cols; tile = 5 dims x 25 params + 3 pad

typedef __attribute__((ext_vector_type(8))) short  short8;   // 8 bf16 (4 VGPRs)
typedef __attribute__((ext_vector_type(4))) float  floatx4;  // MFMA C/D frag
typedef unsigned int u32;

// fast-math scalar helpers (single v_exp / v_log / v_rcp; rel err ~1e-6,
// negligible vs bf16-GEMM-dominated tolerance)
__device__ __forceinline__ float fexp(float x) { return __expf(x); }
__device__ __forceinline__ float flog(float x) { return __logf(x); }
__device__ __forceinline__ float fdiv(float a, float b) { return __fdividef(a, b); }

// async global->LDS, 16B per lane. dst = wave-uniform base + lane*16.
__device__ __forceinline__ void async_copy16(const unsigned short* g,
                                             unsigned short* l) {
    __builtin_amdgcn_global_load_lds(
        (const __attribute__((address_space(1))) u32*)g,
        (__attribute__((address_space(3))) u32*)l,
        16, 0, 0);
}

// XCD-chunked block swizzle (A-panel L2 residency; r5: FETCH 88->55MB, -10us).
// Bijective for grid NT*128 with NT*16 per XCD: m = xcd*16+half*8+msub.
__device__ __forceinline__ void swizzle_bid(int bid, int NT,
                                            int& tile, int& m) {
    const int xcd  = bid & 7;
    const int u    = bid >> 3;          // [0, NT*16)
    const int ph   = NT * 8;
    const int half = u / ph;            // 0..1
    const int rem  = u % ph;
    const int trank = rem >> 3;         // 0..NT-1
    const int msub  = rem & 7;
    tile = NT - 1 - trank;              // long-K first (klim ascending in tile)
    m    = xcd * 16 + half * 8 + msub;  // 0..127
}

// ---------------------------------------------------------------- prep kernels
// merged h1/h2 recovery: blocks [0,HID) do h1 row-reduce; [HID,HID+8) do h2 cols
__global__ __launch_bounds__(128) void hsum_kernel(
    const float* __restrict__ m1, const float* __restrict__ m3,
    int* __restrict__ h1i, int* __restrict__ h2i) {
    const int b = blockIdx.x, t = threadIdx.x;
    if (b < HID) {
        float v = m1[b * DIM + t];
        #pragma unroll
        for (int off = 32; off > 0; off >>= 1) v += __shfl_down(v, off, 64);
        __shared__ float ws[2];
        if ((t & 63) == 0) ws[t >> 6] = v;
        __syncthreads();
        if (t == 0) h1i[b] = (int)(ws[0] + ws[1] + 0.5f);
    } else {
        const int j = (b - HID) * 128 + t;
        float s = 0.f;
        for (int d = 0; d < DIM; d++) s += m3[(size_t)d * OPD * HID + j];
        h2i[j] = DIM - (int)(s + 0.5f);
    }
}

// Counting sort (layer1 by h1, layer2 by h2) + per-tile K bounds. Skipped
// K-region is exact zeros -> bit-identical.
__global__ __launch_bounds__(1024) void sort_kernel(
    const int* __restrict__ h1i, const int* __restrict__ h2i,
    int* __restrict__ perm1, int* __restrict__ perm2,
    int* __restrict__ h1sv, int* __restrict__ h2sv,
    int* __restrict__ klim1, int* __restrict__ klim2, int* __restrict__ klim3)
{
    __shared__ int hist[128];
    __shared__ int h1s[1024], h2s[1024];
    const int t = threadIdx.x;
    const int h1v = h1i[t], h2v = h2i[t];

    if (t < 128) hist[t] = 0;
    __syncthreads();
    atomicAdd(&hist[h1v], 1);
    __syncthreads();
    if (t == 0) { int a = 0; for (int b = 0; b < 128; b++) { int c = hist[b]; hist[b] = a; a += c; } }
    __syncthreads();
    int r = atomicAdd(&hist[h1v], 1);
    perm1[r] = t; h1s[r] = h1v; h1sv[r] = h1v;
    __syncthreads();
    if (t < 128) hist[t] = 0;
    __syncthreads();
    atomicAdd(&hist[h2v], 1);
    __syncthreads();
    if (t == 0) { int a = 0; for (int b = 0; b < 128; b++) { int c = hist[b]; hist[b] = a; a += c; } }
    __syncthreads();
    r = atomicAdd(&hist[h2v], 1);
    perm2[r] = t; h2s[r] = h2v; h2sv[r] = h2v;
    __syncthreads();

    if (t < 8) {
        klim1[t] = ((h1s[t * 128 + 127] + 63) >> 6) << 6;
        int mh = h2s[t * 128 + 127];
        int c = 0;
        for (int j = 0; j < 1024; j++) c += (h1s[j] <= mh) ? 1 : 0;
        klim2[t] = ((c + 63) >> 6) << 6;
    }
    if (t < 26) {
        int dmax = t * 5 + 4; if (dmax > 127) dmax = 127;
        int c = 0;
        for (int j = 0; j < 1024; j++) c += (h2s[j] <= dmax) ? 1 : 0;
        klim3[t] = ((c + 63) >> 6) << 6;
    }
}

// Merged weight-permute + x-cast + lad-zero (r5-verified layout).
// blocks [0,512): w1 | [512,1536): w2 | [1536,4864): w3 | [4864,13056): x/lad
__global__ __launch_bounds__(256) void wperm_kernel(
    const float* __restrict__ W1, const float* __restrict__ b1,
    const float* __restrict__ W2, const float* __restrict__ b2,
    const float* __restrict__ W3, const float* __restrict__ x,
    const int* __restrict__ perm1, const int* __restrict__ perm2,
    const int* __restrict__ h1sv, const int* __restrict__ h2sv,
    __hip_bfloat16* __restrict__ w1p, float* __restrict__ b1p,
    __hip_bfloat16* __restrict__ w2p, float* __restrict__ b2p,
    __hip_bfloat16* __restrict__ w3p,
    __hip_bfloat16* __restrict__ xb, float* __restrict__ lad)
{
    __shared__ float row[HID];
    const int b = blockIdx.x, t = threadIdx.x;
    if (b < 512) {
        // w1p[hp,col] = W1[perm1[hp],col] * (col < h1sv[hp])
        const int i = b * 256 + t;
        const int hp = i >> 7, col = i & 127;
        const int src = perm1[hp];
        float v = (col < h1sv[hp]) ? W1[src * DIM + col] : 0.f;
        w1p[i] = __float2bfloat16(v);
        if (col == 0) b1p[hp] = b1[src];
    } else if (b < 512 + HID) {
        // w2p[ip,jp] = W2[perm2[ip],perm1[jp]] * (h1sv[jp] <= h2sv[ip])
        const int ip = b - 512;
        const int si = perm2[ip];
        const int h2v = h2sv[ip];
        #pragma unroll
        for (int q = 0; q < 4; q++) row[q * 256 + t] = W2[(size_t)si * HID + q * 256 + t];
        __syncthreads();
        #pragma unroll
        for (int q = 0; q < 4; q++) {
            const int jp = q * 256 + t;
            float v = (h1sv[jp] <= h2v) ? row[perm1[jp]] : 0.f;
            w2p[(size_t)ip * HID + jp] = __float2bfloat16(v);
        }
        if (t == 0) b2p[ip] = b2[si];
    } else if (b < 512 + HID + NP) {
        // w3p[c,kk] = W3[t3*125+s, perm2[kk]] * (h2sv[kk] <= d), c=t3*128+s
        const int c = b - 512 - HID;
        const int s = c & 127, t3 = c >> 7;
        if (s >= 125) {
            #pragma unroll
            for (int q = 0; q < 4; q++)
                w3p[(size_t)c * HID + q * 256 + t] = __float2bfloat16(0.f);
            return;
        }
        const int srcrow = t3 * 125 + s;
        const int d = srcrow / 25;
        #pragma unroll
        for (int q = 0; q < 4; q++) row[q * 256 + t] = W3[(size_t)srcrow * HID + q * 256 + t];
        __syncthreads();
        #pragma unroll
        for (int q = 0; q < 4; q++) {
            const int kk = q * 256 + t;
            float v = (h2sv[kk] <= d) ? row[perm2[kk]] : 0.f;
            w3p[(size_t)c * HID + kk] = __float2bfloat16(v);
        }
    } else {
        // x -> bf16 cast + lad zero-init
        const int i = (b - (512 + HID + NP)) * 256 + t;
        xb[i] = __float2bfloat16(x[i]);
        if (i < BATCH) lad[i] = 0.f;
    }
}

// ---------------------------------------------------------------- spline eval
// p[0..7]=uw, p[8..15]=uh, p[16..24]=ud. Fast-math transcendentals.
// r7-verified: renormalize (icw/ich) removed — cw[NK] == 1.0 +- ~1e-6.
__device__ __forceinline__ void spline_eval(const float* __restrict__ p,
                                            float xv, float& yout, float& lout) {
    float cw[NK + 1], ch[NK + 1];
    {
        float mx = p[0];
        #pragma unroll
        for (int j = 1; j < NK; j++) mx = fmaxf(mx, p[j]);
        float e[NK], s = 0.f;
        #pragma unroll
        for (int j = 0; j < NK; j++) { e[j] = fexp(p[j] - mx); s += e[j]; }
        const float inv = fdiv(1.f, s);
        cw[0] = 0.f;
        #pragma unroll
        for (int j = 0; j < NK; j++) cw[j + 1] = cw[j] + (0.001f + 0.992f * e[j] * inv);
    }
    {
        float mx = p[8];
        #pragma unroll
        for (int j = 1; j < NK; j++) mx = fmaxf(mx, p[8 + j]);
        float e[NK], s = 0.f;
        #pragma unroll
        for (int j = 0; j < NK; j++) { e[j] = fexp(p[8 + j] - mx); s += e[j]; }
        const float inv = fdiv(1.f, s);
        ch[0] = 0.f;
        #pragma unroll
        for (int j = 0; j < NK; j++) ch[j + 1] = ch[j] + (0.001f + 0.992f * e[j] * inv);
    }

    const bool inside = (xv >= -3.f) && (xv <= 3.f);
    float xs = (xv + 3.f) * (1.f / 6.f);
    xs = fminf(fmaxf(xs, 0.f), 1.f);
    const float xsc = xs * cw[NK];

    float xk = 0.f, wk = cw[1], yk = 0.f, hk = ch[1];
    float uda = p[16], udb = p[17];
    #pragma unroll
    for (int j = 1; j < NK; j++) {
        const bool c = (xsc >= cw[j]);
        xk  = c ? cw[j] : xk;
        wk  = c ? (cw[j + 1] - cw[j]) : wk;
        yk  = c ? ch[j] : yk;
        hk  = c ? (ch[j + 1] - ch[j]) : hk;
        uda = c ? p[16 + j] : uda;
        udb = c ? p[17 + j] : udb;
    }

    // softplus on the two selected params only
    const float dk  = 0.001f + ((uda > 20.f) ? uda : flog(1.f + fexp(uda)));
    const float dk1 = 0.001f + ((udb > 20.f) ? udb : flog(1.f + fexp(udb)));

    float t = fdiv(xs - xk, wk + 1e-12f);
    t = fminf(fmaxf(t, 0.f), 1.f);
    const float a   = fdiv(hk + 1e-12f, wk + 1e-12f);
    const float omt = 1.f - t;
    const float tt1 = t * omt;
    const float num = a * t * t + dk * tt1;
    const float den = a + (dk + dk1 - 2.f * a) * tt1;
    const float s   = fdiv(num, den + 1e-12f);
    const float y   = (yk + hk * s) * 6.f - 3.f;
    const float dnum = a * a * (dk1 * t * t + 2.f * a * tt1 + dk * omt * omt);
    const float dydx = fdiv(dnum, den * den + 1e-12f);

    yout = inside ? y : xv;
    lout = inside ? flog(fmaxf(dydx, 1e-12f)) : 0.f;
}

// ---------------------------------------------------------------- GEMM (1,2)
// ROUND-0 VERIFIED K-loop (BK=64 single-buffer, __syncthreads pair). XCD
// swizzle. r7-verified vectorized C-write through 32KB eb overlay.
__global__ __launch_bounds__(256, 4) void gemm_bt_kernel(
    const unsigned short* __restrict__ A,
    const unsigned short* __restrict__ Bw,
    const float* __restrict__ bias,
    const int* __restrict__ klim,
    __hip_bfloat16* __restrict__ Cout,
    int M, int N, int Kd)
{
    constexpr int BM = 128, BN = 128, BK = 64;
    __shared__ __align__(16) char smem[32768];
    unsigned short* As = (unsigned short*)smem;            // 16 KB
    unsigned short* Bs = (unsigned short*)(smem + 16384);  // 16 KB
    float* eb = (float*)smem;                              // overlay 64x128 f32

    const int bid = blockIdx.y * gridDim.x + blockIdx.x;
    int tile, mpan;
    swizzle_bid(bid, gridDim.x, tile, mpan);
    const int bn = tile * BN;
    const int bm = mpan * BM;
    const int Klim = klim[tile];

    const int t    = threadIdx.x;
    const int lane = t & 63;
    const int w    = t >> 6;
    const int wr   = (w >> 1) * 64;
    const int wc   = (w & 1) * 64;
    const int lr   = lane & 15;
    const int quad = lane >> 4;
    const int lxor = lr & 7;

    floatx4 acc[4][4] = {};

    const int lrow = lane >> 3;
    const int lcol = ((lane & 7) ^ lrow) * 8;

    for (int k0 = 0; k0 < Klim; k0 += BK) {
        __syncthreads();
        #pragma unroll
        for (int p = 0; p < 4; p++) {
            const int q = w * 4 + p;
            const int r = q * 8 + lrow;
            async_copy16(&A[(size_t)(bm + r) * Kd + k0 + lcol],
                         &As[q * 512 + lane * 8]);
            async_copy16(&Bw[(size_t)(bn + r) * Kd + k0 + lcol],
                         &Bs[q * 512 + lane * 8]);
        }
        __syncthreads();
        #pragma unroll
        for (int ks = 0; ks < BK; ks += 32) {
            const int cbase = (ks >> 3) + quad;
            const int coff  = (cbase ^ lxor) * 8;
            short8 af[4], bfr[4];
            #pragma unroll
            for (int i = 0; i < 4; i++)
                af[i] = *(const short8*)&As[(wr + i * 16 + lr) * BK + coff];
            #pragma unroll
            for (int j = 0; j < 4; j++)
                bfr[j] = *(const short8*)&Bs[(wc + j * 16 + lr) * BK + coff];
            #pragma unroll
            for (int i = 0; i < 4; i++)
                #pragma unroll
                for (int j = 0; j < 4; j++)
                    acc[i][j] = __builtin_amdgcn_mfma_f32_16x16x32_bf16(
                        af[i], bfr[j], acc[i][j], 0, 0, 0);
        }
    }

    // ---- vectorized epilogue: two 64-row halves through eb ----
    #pragma unroll 1
    for (int h = 0; h < 2; h++) {
        __syncthreads();                       // drains lgkm+vm: safe overlay
        if ((w >> 1) == h) {
            #pragma unroll
            for (int j = 0; j < 4; j++) {
                const int s = wc + j * 16 + lr;
                const float bv = bias[bn + s];
                #pragma unroll
                for (int i = 0; i < 4; i++) {
                    const int lrw = i * 16 + quad * 4;
                    #pragma unroll
                    for (int r2 = 0; r2 < 4; r2++)
                        eb[(lrw + r2) * 128 + s] = acc[i][j][r2] + bv;
                }
            }
        }
        __syncthreads();
        #pragma unroll
        for (int it = 0; it < 4; it++) {
            const int idx = it * 256 + t;
            const int row = idx >> 4;
            const int c0  = (idx & 15) << 3;
            const floatx4 v0 = *(const floatx4*)&eb[row * 128 + c0];
            const floatx4 v1 = *(const floatx4*)&eb[row * 128 + c0 + 4];
            short8 o;
            #pragma unroll
            for (int e = 0; e < 4; e++) {
                float a0 = v0[e];
                a0 = a0 * fdiv(1.f, 1.f + fexp(-a0));   // fast silu
                union { __hip_bfloat16 b; unsigned short u; } c0v;
                c0v.b = __float2bfloat16(a0);
                o[e] = (short)c0v.u;
                float a1 = v1[e];
                a1 = a1 * fdiv(1.f, 1.f + fexp(-a1));
                union { __hip_bfloat16 b; unsigned short u; } c1v;
                c1v.b = __float2bfloat16(a1);
                o[e + 4] = (short)c1v.u;
            }
            *(short8*)&Cout[(size_t)(bm + h * 64 + row) * N + bn + c0] = o;
        }
    }
}

// ---------------------------------------------------------------- GEMM3+spline
// r8: PAIRED TILES (BN=256, shared A). Tiles 2t,2t+1 are contiguous w3p rows;
// both run to max(klim) — w3p is exactly zero beyond each tile's mask bound,
// so the extra K-range accumulates zeros: bit-identical. Per K-step: stage A
// once + 2 B tiles, 64 MFMA/wave (was 32) -> drain events per unit work -48%,
// staged bytes/MFMA -25%. LDS 48KB -> 3 blocks/CU (= measured effective
// occupancy already). Epilogue: 2 sequential per-tile passes (EPIPASS macro,
// literal acc names — no runtime acc indexing, rule #20).
__global__ __launch_bounds__(256, 4) void gemm3_spline_kernel(
    const unsigned short* __restrict__ A,    // h2b M x HID (perm2 col order)
    const unsigned short* __restrict__ Bw,   // w3p NP x HID (perm2 col order)
    const float* __restrict__ b3,            // N3 (original layout)
    const int* __restrict__ klim,            // [26]
    const float* __restrict__ x,             // M x DIM fp32
    float* __restrict__ out,                 // M x DIM
    float* __restrict__ lad,                 // M, pre-zeroed
    int M)
{
    constexpr int BM = 128, BK = 64, Kd = HID;
    constexpr int GS = 28;                            // padded group stride (floats)
    constexpr int RS = 140;                           // padded row stride (floats)
    // GEMM phase: As 16KB [0,16K) + Bs 32KB [16K,48K).
    // Epilogue overlay: eb 35840B + ladacc 512B @35840 (zeroed after K-loop!).
    __shared__ __align__(16) char smem[49152];
    unsigned short* As = (unsigned short*)smem;
    unsigned short* Bs = (unsigned short*)(smem + 16384);  // 256 rows x 64 cols
    float* eb     = (float*)smem;
    float* ladacc = (float*)(smem + 64 * RS * 4);     // [128]

    const int bid = blockIdx.y * gridDim.x + blockIdx.x;
    int pair, mpan;
    swizzle_bid(bid, gridDim.x, pair, mpan);          // NT = 13 pairs
    const int bn2 = pair * 256;
    const int bm  = mpan * BM;
    const int k0a = klim[2 * pair], k0b = klim[2 * pair + 1];
    const int Klim = (k0a > k0b) ? k0a : k0b;

    const int t    = threadIdx.x;
    const int lane = t & 63;
    const int w    = t >> 6;
    const int wr   = (w >> 1) * 64;
    const int wc   = (w & 1) * 64;
    const int lr   = lane & 15;
    const int quad = lane >> 4;
    const int lxor = lr & 7;

    floatx4 acc0[4][4] = {};
    floatx4 acc1[4][4] = {};

    const int lrow = lane >> 3;
    const int lcol = ((lane & 7) ^ lrow) * 8;

    for (int k0 = 0; k0 < Klim; k0 += BK) {
        __syncthreads();
        #pragma unroll
        for (int p = 0; p < 4; p++) {                 // A: 128 rows
            const int q = w * 4 + p;
            const int r = q * 8 + lrow;
            async_copy16(&A[(size_t)(bm + r) * Kd + k0 + lcol],
                         &As[q * 512 + lane * 8]);
        }
        #pragma unroll
        for (int p = 0; p < 8; p++) {                 // B: 256 rows (both tiles)
            const int q = w * 8 + p;
            const int r = q * 8 + lrow;
            async_copy16(&Bw[(size_t)(bn2 + r) * Kd + k0 + lcol],
                         &Bs[q * 512 + lane * 8]);
        }
        __syncthreads();
        #pragma unroll
        for (int ks = 0; ks < BK; ks += 32) {
            const int cbase = (ks >> 3) + quad;
            const int coff  = (cbase ^ lxor) * 8;
            short8 af[4], bfr[4];
            #pragma unroll
            for (int i = 0; i < 4; i++)
                af[i] = *(const short8*)&As[(wr + i * 16 + lr) * BK + coff];
            // tile 0 of pair
            #pragma unroll
            for (int j = 0; j < 4; j++)
                bfr[j] = *(const short8*)&Bs[(wc + j * 16 + lr) * BK + coff];
            #pragma unroll
            for (int i = 0; i < 4; i++)
                #pragma unroll
                for (int j = 0; j < 4; j++)
                    acc0[i][j] = __builtin_amdgcn_mfma_f32_16x16x32_bf16(
                        af[i], bfr[j], acc0[i][j], 0, 0, 0);
            // tile 1 of pair (B rows 128..255)
            #pragma unroll
            for (int j = 0; j < 4; j++)
                bfr[j] = *(const short8*)&Bs[(128 + wc + j * 16 + lr) * BK + coff];
            #pragma unroll
            for (int i = 0; i < 4; i++)
                #pragma unroll
                for (int j = 0; j < 4; j++)
                    acc1[i][j] = __builtin_amdgcn_mfma_f32_16x16x32_bf16(
                        af[i], bfr[j], acc1[i][j], 0, 0, 0);
        }
    }

    // ---- fused epilogue: 2 tiles x 2 half passes ----
    // ladacc lives inside the Bs region during GEMM -> zero it in first pass
    // (after the first sync, before any eval reads it).
#define EPIPASS(ACC_, TH_)                                                     \
    {                                                                          \
        const int tile = pair * 2 + TH_;                                       \
        _Pragma("unroll 1")                                                    \
        for (int h = 0; h < 2; h++) {                                          \
            __syncthreads();                                                   \
            if (TH_ == 0 && h == 0 && t < 128) ladacc[t] = 0.f;                \
            if ((w >> 1) == h) {                                               \
                _Pragma("unroll")                                              \
                for (int j = 0; j < 4; j++) {                                  \
                    const int s = wc + j * 16 + lr;                            \
                    if (s < 125) {                                             \
                        const int grp = s / 25, within = s % 25;               \
                        const int off = grp * GS + within;                     \
                        const int bidx = tile * 125 + s;                       \
                        const float bv = b3[bidx < N3 ? bidx : 0];             \
                        _Pragma("unroll")                                      \
                        for (int i = 0; i < 4; i++) {                          \
                            const int lrw = i * 16 + quad * 4;                 \
                            _Pragma("unroll")                                  \
                            for (int r2 = 0; r2 < 4; r2++)                     \
                                eb[(lrw + r2) * RS + off] =                    \
                                    ACC_[i][j][r2] + bv;                       \
                        }                                                      \
                    }                                                          \
                }                                                              \
            }                                                                  \
            __syncthreads();                                                   \
            _Pragma("unroll 1")                                                \
            for (int q = t; q < 320; q += 256) {                               \
                const int r  = q / 5;                                          \
                const int ds = q % 5;                                          \
                const int dim = tile * 5 + ds;                                 \
                if (dim < DIM) {                                               \
                    float pl[28];                                              \
                    const floatx4* pv = (const floatx4*)(eb + r * RS + ds * GS);\
                    _Pragma("unroll")                                          \
                    for (int ii = 0; ii < 7; ii++) ((floatx4*)pl)[ii] = pv[ii];\
                    const int grow = bm + h * 64 + r;                          \
                    const float xv = x[(size_t)grow * DIM + dim];              \
                    float y, l;                                                \
                    spline_eval(pl, xv, y, l);                                 \
                    out[(size_t)grow * DIM + dim] = y;                         \
                    atomicAdd(&ladacc[h * 64 + r], l);                         \
                }                                                              \
            }                                                                  \
        }                                                                      \
    }

    EPIPASS(acc0, 0)
    EPIPASS(acc1, 1)
#undef EPIPASS

    __syncthreads();
    if (t < 128) atomicAdd(&lad[bm + t], ladacc[t]);
}

// ---------------------------------------------------------------- launch
extern "C" void kernel_launch(void* const* d_in, const int* in_sizes, int n_in,
                              void* d_out, int out_size, void* d_ws, size_t ws_size,
                              hipStream_t stream) {
    const float* x  = (const float*)d_in[0];
    const float* W1 = (const float*)d_in[1];
    const float* b1 = (const float*)d_in[2];
    const float* W2 = (const float*)d_in[3];
    const float* b2 = (const float*)d_in[4];
    const float* W3 = (const float*)d_in[5];
    const float* b3 = (const float*)d_in[6];
    const float* m1 = (const float*)d_in[7];
    const float* m3 = (const float*)d_in[9];

    // workspace: ~81 MB + small arrays
    char* ws = (char*)d_ws;
    const size_t OFF_W1B = 0;
    const size_t OFF_W2B = OFF_W1B + (size_t)HID * DIM * 2;
    const size_t OFF_W3P = OFF_W2B + (size_t)HID * HID * 2;
    const size_t OFF_XB  = OFF_W3P + (size_t)NP * HID * 2;
    const size_t OFF_H1B = OFF_XB  + (size_t)BATCH * DIM * 2;
    const size_t OFF_H2B = OFF_H1B + (size_t)BATCH * HID * 2;
    const size_t OFF_SML = OFF_H2B + (size_t)BATCH * HID * 2;

    __hip_bfloat16* w1p = (__hip_bfloat16*)(ws + OFF_W1B);
    __hip_bfloat16* w2p = (__hip_bfloat16*)(ws + OFF_W2B);
    __hip_bfloat16* w3p = (__hip_bfloat16*)(ws + OFF_W3P);
    __hip_bfloat16* xb  = (__hip_bfloat16*)(ws + OFF_XB);
    __hip_bfloat16* h1b = (__hip_bfloat16*)(ws + OFF_H1B);
    __hip_bfloat16* h2b = (__hip_bfloat16*)(ws + OFF_H2B);

    float* b1p   = (float*)(ws + OFF_SML);
    float* b2p   = b1p + HID;
    int*   h1i   = (int*)(b2p + HID);
    int*   h2i   = h1i + HID;
    int*   perm1 = h2i + HID;
    int*   perm2 = perm1 + HID;
    int*   h1sv  = perm2 + HID;
    int*   h2sv  = h1sv + HID;
    int*   klim1 = h2sv + HID;
    int*   klim2 = klim1 + 8;
    int*   klim3 = klim2 + 8;

    float* out_p = (float*)d_out;
    float* lad_p = out_p + (size_t)BATCH * DIM;

    // prep (r5/r7-verified structure)
    hsum_kernel<<<HID + 8, 128, 0, stream>>>(m1, m3, h1i, h2i);
    sort_kernel<<<1, 1024, 0, stream>>>(h1i, h2i, perm1, perm2, h1sv, h2sv,
                                        klim1, klim2, klim3);
    wperm_kernel<<<512 + HID + NP + (BATCH * DIM) / 256, 256, 0, stream>>>(
        W1, b1, W2, b2, W3, x, perm1, perm2, h1sv, h2sv,
        w1p, b1p, w2p, b2p, w3p, xb, lad_p);

    // GEMMs (per-tile K bounds from sorted-mask prefixes)
    gemm_bt_kernel<<<dim3(HID / 128, BATCH / 128), 256, 0, stream>>>(
        (const unsigned short*)xb, (const unsigned short*)w1p, b1p, klim1, h1b,
        BATCH, HID, DIM);
    gemm_bt_kernel<<<dim3(HID / 128, BATCH / 128), 256, 0, stream>>>(
        (const unsigned short*)h1b, (const unsigned short*)w2p, b2p, klim2, h2b,
        BATCH, HID, HID);
    // paired-tile gemm3: 13 pairs x 128 m-panels
    gemm3_spline_kernel<<<dim3(13, BATCH / 128), 256, 0, stream>>>(
        (const unsigned short*)h2b, (const unsigned short*)w3p, b3, klim3, x,
        out_p, lad_p, BATCH);
}

// Round 10
// 263.505 us; speedup vs baseline: 1.3873x; 1.3873x over previous
//
#include <hip/hip_runtime.h>
#include <hip/hip_bf16.h>

// Problem constants (from reference)
#define BATCH 16384
#define DIM   128
#define HID   1024
#define NK    8
#define OPD   25          // 3*K+1
#define N3    (DIM*OPD)   // 3200
#define NP    3328        // 26 tiles x 128 cols; tile = 5 dims x 25 params + 3 pad

typedef __attribute__((ext_vector_type(8))) short  short8;   // 8 bf16 (4 VGPRs)
typedef __attribute__((ext_vector_type(4))) float  floatx4;  // MFMA C/D frag
typedef unsigned int u32;

// fast-math scalar helpers (single v_exp / v_log / v_rcp; rel err ~1e-6,
// negligible vs bf16-GEMM-dominated tolerance)
__device__ __forceinline__ float fexp(float x) { return __expf(x); }
__device__ __forceinline__ float flog(float x) { return __logf(x); }
__device__ __forceinline__ float fdiv(float a, float b) { return __fdividef(a, b); }

// async global->LDS, 16B per lane. dst = wave-uniform base + lane*16.
__device__ __forceinline__ void async_copy16(const unsigned short* g,
                                             unsigned short* l) {
    __builtin_amdgcn_global_load_lds(
        (const __attribute__((address_space(1))) u32*)g,
        (__attribute__((address_space(3))) u32*)l,
        16, 0, 0);
}

// XCD-chunked block swizzle (A-panel L2 residency; r5: FETCH 88->55MB, -10us).
// Bijective for grid NT*128 with NT*16 per XCD: m = xcd*16+half*8+msub.
__device__ __forceinline__ void swizzle_bid(int bid, int NT,
                                            int& tile, int& m) {
    const int xcd  = bid & 7;
    const int u    = bid >> 3;          // [0, NT*16)
    const int ph   = NT * 8;
    const int half = u / ph;            // 0..1
    const int rem  = u % ph;
    const int trank = rem >> 3;         // 0..NT-1
    const int msub  = rem & 7;
    tile = NT - 1 - trank;              // long-K first (klim ascending in tile)
    m    = xcd * 16 + half * 8 + msub;  // 0..127
}

// ---------------------------------------------------------------- prep kernels
// r9: fully-parallel prep-A.
//  blocks [0,1024):    h1 row-reduce (as before)
//  blocks [1024,2048): h2 col-reduce — ONE BLOCK PER COLUMN, thread t = d.
//    (old form: 8 blocks x 128-iter serial uncoalesced loop = latency-bound
//     tail with GPU ~idle; now 131K independent loads fully parallel)
//  blocks [2048,4096): x->bf16 cast (short8 vectorized) + lad zero
__global__ __launch_bounds__(128) void hsum_kernel(
    const float* __restrict__ m1, const float* __restrict__ m3,
    const float* __restrict__ x,
    __hip_bfloat16* __restrict__ xb, float* __restrict__ lad,
    int* __restrict__ h1i, int* __restrict__ h2i) {
    const int b = blockIdx.x, t = threadIdx.x;
    if (b < HID) {
        float v = m1[b * DIM + t];
        #pragma unroll
        for (int off = 32; off > 0; off >>= 1) v += __shfl_down(v, off, 64);
        __shared__ float ws[2];
        if ((t & 63) == 0) ws[t >> 6] = v;
        __syncthreads();
        if (t == 0) h1i[b] = (int)(ws[0] + ws[1] + 0.5f);
    } else if (b < 2 * HID) {
        const int j = b - HID;                      // column 0..1023
        float v = m3[(size_t)t * OPD * HID + j];    // d = t (one load/thread)
        #pragma unroll
        for (int off = 32; off > 0; off >>= 1) v += __shfl_down(v, off, 64);
        __shared__ float ws2[2];
        if ((t & 63) == 0) ws2[t >> 6] = v;
        __syncthreads();
        if (t == 0) h2i[j] = DIM - (int)(ws2[0] + ws2[1] + 0.5f);
    } else {
        // cast 1024 elems per block, 8 per thread (vectorized)
        const int i8 = (b - 2 * HID) * 1024 + t * 8;
        const floatx4 v0 = *(const floatx4*)&x[i8];
        const floatx4 v1 = *(const floatx4*)&x[i8 + 4];
        short8 o;
        #pragma unroll
        for (int e = 0; e < 4; e++) {
            union { __hip_bfloat16 bb; unsigned short u; } c0, c1;
            c0.bb = __float2bfloat16(v0[e]);
            c1.bb = __float2bfloat16(v1[e]);
            o[e] = (short)c0.u; o[e + 4] = (short)c1.u;
        }
        *(short8*)&xb[i8] = o;
        if (i8 < BATCH) {                           // BATCH % 8 == 0
            *(floatx4*)&lad[i8] = (floatx4){0.f, 0.f, 0.f, 0.f};
            *(floatx4*)&lad[i8 + 4] = (floatx4){0.f, 0.f, 0.f, 0.f};
        }
    }
}

// Counting sort (layer1 by h1, layer2 by h2) + per-tile K bounds. Skipped
// K-region is exact zeros -> bit-identical.
__global__ __launch_bounds__(1024) void sort_kernel(
    const int* __restrict__ h1i, const int* __restrict__ h2i,
    int* __restrict__ perm1, int* __restrict__ perm2,
    int* __restrict__ h1sv, int* __restrict__ h2sv,
    int* __restrict__ klim1, int* __restrict__ klim2, int* __restrict__ klim3)
{
    __shared__ int hist[128];
    __shared__ int h1s[1024], h2s[1024];
    const int t = threadIdx.x;
    const int h1v = h1i[t], h2v = h2i[t];

    if (t < 128) hist[t] = 0;
    __syncthreads();
    atomicAdd(&hist[h1v], 1);
    __syncthreads();
    if (t == 0) { int a = 0; for (int b = 0; b < 128; b++) { int c = hist[b]; hist[b] = a; a += c; } }
    __syncthreads();
    int r = atomicAdd(&hist[h1v], 1);
    perm1[r] = t; h1s[r] = h1v; h1sv[r] = h1v;
    __syncthreads();
    if (t < 128) hist[t] = 0;
    __syncthreads();
    atomicAdd(&hist[h2v], 1);
    __syncthreads();
    if (t == 0) { int a = 0; for (int b = 0; b < 128; b++) { int c = hist[b]; hist[b] = a; a += c; } }
    __syncthreads();
    r = atomicAdd(&hist[h2v], 1);
    perm2[r] = t; h2s[r] = h2v; h2sv[r] = h2v;
    __syncthreads();

    if (t < 8) {
        klim1[t] = ((h1s[t * 128 + 127] + 63) >> 6) << 6;
        int mh = h2s[t * 128 + 127];
        int c = 0;
        for (int j = 0; j < 1024; j++) c += (h1s[j] <= mh) ? 1 : 0;
        klim2[t] = ((c + 63) >> 6) << 6;
    }
    if (t < 26) {
        int dmax = t * 5 + 4; if (dmax > 127) dmax = 127;
        int c = 0;
        for (int j = 0; j < 1024; j++) c += (h2s[j] <= dmax) ? 1 : 0;
        klim3[t] = ((c + 63) >> 6) << 6;
    }
}

// Weight-permute: blocks [0,512) w1 | [512,1536) w2 | [1536,4864) w3
// (x-cast moved to hsum_kernel in r9)
__global__ __launch_bounds__(256) void wperm_kernel(
    const float* __restrict__ W1, const float* __restrict__ b1,
    const float* __restrict__ W2, const float* __restrict__ b2,
    const float* __restrict__ W3,
    const int* __restrict__ perm1, const int* __restrict__ perm2,
    const int* __restrict__ h1sv, const int* __restrict__ h2sv,
    __hip_bfloat16* __restrict__ w1p, float* __restrict__ b1p,
    __hip_bfloat16* __restrict__ w2p, float* __restrict__ b2p,
    __hip_bfloat16* __restrict__ w3p)
{
    __shared__ float row[HID];
    const int b = blockIdx.x, t = threadIdx.x;
    if (b < 512) {
        // w1p[hp,col] = W1[perm1[hp],col] * (col < h1sv[hp])
        const int i = b * 256 + t;
        const int hp = i >> 7, col = i & 127;
        const int src = perm1[hp];
        float v = (col < h1sv[hp]) ? W1[src * DIM + col] : 0.f;
        w1p[i] = __float2bfloat16(v);
        if (col == 0) b1p[hp] = b1[src];
    } else if (b < 512 + HID) {
        // w2p[ip,jp] = W2[perm2[ip],perm1[jp]] * (h1sv[jp] <= h2sv[ip])
        const int ip = b - 512;
        const int si = perm2[ip];
        const int h2v = h2sv[ip];
        #pragma unroll
        for (int q = 0; q < 4; q++) row[q * 256 + t] = W2[(size_t)si * HID + q * 256 + t];
        __syncthreads();
        #pragma unroll
        for (int q = 0; q < 4; q++) {
            const int jp = q * 256 + t;
            float v = (h1sv[jp] <= h2v) ? row[perm1[jp]] : 0.f;
            w2p[(size_t)ip * HID + jp] = __float2bfloat16(v);
        }
        if (t == 0) b2p[ip] = b2[si];
    } else {
        // w3p[c,kk] = W3[t3*125+s, perm2[kk]] * (h2sv[kk] <= d), c=t3*128+s
        const int c = b - 512 - HID;
        const int s = c & 127, t3 = c >> 7;
        if (s >= 125) {
            #pragma unroll
            for (int q = 0; q < 4; q++)
                w3p[(size_t)c * HID + q * 256 + t] = __float2bfloat16(0.f);
            return;
        }
        const int srcrow = t3 * 125 + s;
        const int d = srcrow / 25;
        #pragma unroll
        for (int q = 0; q < 4; q++) row[q * 256 + t] = W3[(size_t)srcrow * HID + q * 256 + t];
        __syncthreads();
        #pragma unroll
        for (int q = 0; q < 4; q++) {
            const int kk = q * 256 + t;
            float v = (h2sv[kk] <= d) ? row[perm2[kk]] : 0.f;
            w3p[(size_t)c * HID + kk] = __float2bfloat16(v);
        }
    }
}

// ---------------------------------------------------------------- spline eval
// p[0..7]=uw, p[8..15]=uh, p[16..24]=ud. Fast-math transcendentals.
// r7-verified: renormalize (icw/ich) removed — cw[NK] == 1.0 +- ~1e-6.
__device__ __forceinline__ void spline_eval(const float* __restrict__ p,
                                            float xv, float& yout, float& lout) {
    float cw[NK + 1], ch[NK + 1];
    {
        float mx = p[0];
        #pragma unroll
        for (int j = 1; j < NK; j++) mx = fmaxf(mx, p[j]);
        float e[NK], s = 0.f;
        #pragma unroll
        for (int j = 0; j < NK; j++) { e[j] = fexp(p[j] - mx); s += e[j]; }
        const float inv = fdiv(1.f, s);
        cw[0] = 0.f;
        #pragma unroll
        for (int j = 0; j < NK; j++) cw[j + 1] = cw[j] + (0.001f + 0.992f * e[j] * inv);
    }
    {
        float mx = p[8];
        #pragma unroll
        for (int j = 1; j < NK; j++) mx = fmaxf(mx, p[8 + j]);
        float e[NK], s = 0.f;
        #pragma unroll
        for (int j = 0; j < NK; j++) { e[j] = fexp(p[8 + j] - mx); s += e[j]; }
        const float inv = fdiv(1.f, s);
        ch[0] = 0.f;
        #pragma unroll
        for (int j = 0; j < NK; j++) ch[j + 1] = ch[j] + (0.001f + 0.992f * e[j] * inv);
    }

    const bool inside = (xv >= -3.f) && (xv <= 3.f);
    float xs = (xv + 3.f) * (1.f / 6.f);
    xs = fminf(fmaxf(xs, 0.f), 1.f);
    const float xsc = xs * cw[NK];

    float xk = 0.f, wk = cw[1], yk = 0.f, hk = ch[1];
    float uda = p[16], udb = p[17];
    #pragma unroll
    for (int j = 1; j < NK; j++) {
        const bool c = (xsc >= cw[j]);
        xk  = c ? cw[j] : xk;
        wk  = c ? (cw[j + 1] - cw[j]) : wk;
        yk  = c ? ch[j] : yk;
        hk  = c ? (ch[j + 1] - ch[j]) : hk;
        uda = c ? p[16 + j] : uda;
        udb = c ? p[17 + j] : udb;
    }

    // softplus on the two selected params only
    const float dk  = 0.001f + ((uda > 20.f) ? uda : flog(1.f + fexp(uda)));
    const float dk1 = 0.001f + ((udb > 20.f) ? udb : flog(1.f + fexp(udb)));

    float t = fdiv(xs - xk, wk + 1e-12f);
    t = fminf(fmaxf(t, 0.f), 1.f);
    const float a   = fdiv(hk + 1e-12f, wk + 1e-12f);
    const float omt = 1.f - t;
    const float tt1 = t * omt;
    const float num = a * t * t + dk * tt1;
    const float den = a + (dk + dk1 - 2.f * a) * tt1;
    const float s   = fdiv(num, den + 1e-12f);
    const float y   = (yk + hk * s) * 6.f - 3.f;
    const float dnum = a * a * (dk1 * t * t + 2.f * a * tt1 + dk * omt * omt);
    const float dydx = fdiv(dnum, den * den + 1e-12f);

    yout = inside ? y : xv;
    lout = inside ? flog(fmaxf(dydx, 1e-12f)) : 0.f;
}

// ---------------------------------------------------------------- GEMM (1,2)
// ROUND-0 VERIFIED K-loop (BK=64 single-buffer, __syncthreads pair). XCD
// swizzle. r7-verified vectorized C-write through 32KB eb overlay.
__global__ __launch_bounds__(256, 4) void gemm_bt_kernel(
    const unsigned short* __restrict__ A,
    const unsigned short* __restrict__ Bw,
    const float* __restrict__ bias,
    const int* __restrict__ klim,
    __hip_bfloat16* __restrict__ Cout,
    int M, int N, int Kd)
{
    constexpr int BM = 128, BN = 128, BK = 64;
    __shared__ __align__(16) char smem[32768];
    unsigned short* As = (unsigned short*)smem;            // 16 KB
    unsigned short* Bs = (unsigned short*)(smem + 16384);  // 16 KB
    float* eb = (float*)smem;                              // overlay 64x128 f32

    const int bid = blockIdx.y * gridDim.x + blockIdx.x;
    int tile, mpan;
    swizzle_bid(bid, gridDim.x, tile, mpan);
    const int bn = tile * BN;
    const int bm = mpan * BM;
    const int Klim = klim[tile];

    const int t    = threadIdx.x;
    const int lane = t & 63;
    const int w    = t >> 6;
    const int wr   = (w >> 1) * 64;
    const int wc   = (w & 1) * 64;
    const int lr   = lane & 15;
    const int quad = lane >> 4;
    const int lxor = lr & 7;

    floatx4 acc[4][4] = {};

    const int lrow = lane >> 3;
    const int lcol = ((lane & 7) ^ lrow) * 8;

    for (int k0 = 0; k0 < Klim; k0 += BK) {
        __syncthreads();
        #pragma unroll
        for (int p = 0; p < 4; p++) {
            const int q = w * 4 + p;
            const int r = q * 8 + lrow;
            async_copy16(&A[(size_t)(bm + r) * Kd + k0 + lcol],
                         &As[q * 512 + lane * 8]);
            async_copy16(&Bw[(size_t)(bn + r) * Kd + k0 + lcol],
                         &Bs[q * 512 + lane * 8]);
        }
        __syncthreads();
        #pragma unroll
        for (int ks = 0; ks < BK; ks += 32) {
            const int cbase = (ks >> 3) + quad;
            const int coff  = (cbase ^ lxor) * 8;
            short8 af[4], bfr[4];
            #pragma unroll
            for (int i = 0; i < 4; i++)
                af[i] = *(const short8*)&As[(wr + i * 16 + lr) * BK + coff];
            #pragma unroll
            for (int j = 0; j < 4; j++)
                bfr[j] = *(const short8*)&Bs[(wc + j * 16 + lr) * BK + coff];
            #pragma unroll
            for (int i = 0; i < 4; i++)
                #pragma unroll
                for (int j = 0; j < 4; j++)
                    acc[i][j] = __builtin_amdgcn_mfma_f32_16x16x32_bf16(
                        af[i], bfr[j], acc[i][j], 0, 0, 0);
        }
    }

    // ---- vectorized epilogue: two 64-row halves through eb ----
    #pragma unroll 1
    for (int h = 0; h < 2; h++) {
        __syncthreads();                       // drains lgkm+vm: safe overlay
        if ((w >> 1) == h) {
            #pragma unroll
            for (int j = 0; j < 4; j++) {
                const int s = wc + j * 16 + lr;
                const float bv = bias[bn + s];
                #pragma unroll
                for (int i = 0; i < 4; i++) {
                    const int lrw = i * 16 + quad * 4;
                    #pragma unroll
                    for (int r2 = 0; r2 < 4; r2++)
                        eb[(lrw + r2) * 128 + s] = acc[i][j][r2] + bv;
                }
            }
        }
        __syncthreads();
        #pragma unroll
        for (int it = 0; it < 4; it++) {
            const int idx = it * 256 + t;
            const int row = idx >> 4;
            const int c0  = (idx & 15) << 3;
            const floatx4 v0 = *(const floatx4*)&eb[row * 128 + c0];
            const floatx4 v1 = *(const floatx4*)&eb[row * 128 + c0 + 4];
            short8 o;
            #pragma unroll
            for (int e = 0; e < 4; e++) {
                float a0 = v0[e];
                a0 = a0 * fdiv(1.f, 1.f + fexp(-a0));   // fast silu
                union { __hip_bfloat16 b; unsigned short u; } c0v;
                c0v.b = __float2bfloat16(a0);
                o[e] = (short)c0v.u;
                float a1 = v1[e];
                a1 = a1 * fdiv(1.f, 1.f + fexp(-a1));
                union { __hip_bfloat16 b; unsigned short u; } c1v;
                c1v.b = __float2bfloat16(a1);
                o[e + 4] = (short)c1v.u;
            }
            *(short8*)&Cout[(size_t)(bm + h * 64 + row) * N + bn + c0] = o;
        }
    }
}

// ---------------------------------------------------------------- GEMM3+spline
// r7-EXACT VERIFIED version (90 us): 128x128 tile, round-0 K-loop, XCD
// swizzle, padded epilogue (GS=28/RS=140 -> 7 x ds_read_b128).
// r8's paired-tile BN=256 variant REGRESSED (VGPR 64->188, occ 38->11%,
// 90->192 us): output area/thread fixes acc budget — do not grow the tile.
__global__ __launch_bounds__(256, 4) void gemm3_spline_kernel(
    const unsigned short* __restrict__ A,    // h2b M x HID (perm2 col order)
    const unsigned short* __restrict__ Bw,   // w3p NP x HID (perm2 col order)
    const float* __restrict__ b3,            // N3 (original layout)
    const int* __restrict__ klim,            // [26]
    const float* __restrict__ x,             // M x DIM fp32
    float* __restrict__ out,                 // M x DIM
    float* __restrict__ lad,                 // M, pre-zeroed
    int M)
{
    constexpr int BM = 128, BN = 128, BK = 64, Kd = HID;
    constexpr int GS = 28;                            // padded group stride (floats)
    constexpr int RS = 140;                           // padded row stride (floats)
    __shared__ __align__(16) char smem[64 * RS * 4 + 128 * 4];  // 36,352 B
    unsigned short* As = (unsigned short*)smem;       // 16 KB
    unsigned short* Bs = (unsigned short*)(smem + BM * BK * 2);
    float* eb     = (float*)smem;
    float* ladacc = (float*)(smem + 64 * RS * 4);     // [128], beyond eb

    const int bid = blockIdx.y * gridDim.x + blockIdx.x;
    int tile, mpan;
    swizzle_bid(bid, gridDim.x, tile, mpan);          // NT = 26
    const int bn = tile * BN;
    const int bm = mpan * BM;
    const int Klim = klim[tile];

    const int t    = threadIdx.x;
    const int lane = t & 63;
    const int w    = t >> 6;
    const int wr   = (w >> 1) * 64;
    const int wc   = (w & 1) * 64;
    const int lr   = lane & 15;
    const int quad = lane >> 4;
    const int lxor = lr & 7;

    if (t < 128) ladacc[t] = 0.f;

    floatx4 acc[4][4] = {};

    const int lrow = lane >> 3;
    const int lcol = ((lane & 7) ^ lrow) * 8;

    for (int k0 = 0; k0 < Klim; k0 += BK) {
        __syncthreads();
        #pragma unroll
        for (int p = 0; p < 4; p++) {
            const int q = w * 4 + p;
            const int r = q * 8 + lrow;
            async_copy16(&A[(size_t)(bm + r) * Kd + k0 + lcol],
                         &As[q * 512 + lane * 8]);
            async_copy16(&Bw[(size_t)(bn + r) * Kd + k0 + lcol],
                         &Bs[q * 512 + lane * 8]);
        }
        __syncthreads();
        #pragma unroll
        for (int ks = 0; ks < BK; ks += 32) {
            const int cbase = (ks >> 3) + quad;
            const int coff  = (cbase ^ lxor) * 8;
            short8 af[4], bfr[4];
            #pragma unroll
            for (int i = 0; i < 4; i++)
                af[i] = *(const short8*)&As[(wr + i * 16 + lr) * BK + coff];
            #pragma unroll
            for (int j = 0; j < 4; j++)
                bfr[j] = *(const short8*)&Bs[(wc + j * 16 + lr) * BK + coff];
            #pragma unroll
            for (int i = 0; i < 4; i++)
                #pragma unroll
                for (int j = 0; j < 4; j++)
                    acc[i][j] = __builtin_amdgcn_mfma_f32_16x16x32_bf16(
                        af[i], bfr[j], acc[i][j], 0, 0, 0);
        }
    }

    // ---- fused epilogue: two 64-row halves ----
    #pragma unroll 1
    for (int h = 0; h < 2; h++) {
        __syncthreads();                              // drains lgkm+vm: safe overlay
        if ((w >> 1) == h) {
            #pragma unroll
            for (int j = 0; j < 4; j++) {
                const int s = wc + j * 16 + lr;
                if (s < 125) {                        // s>=125 would alias next row
                    const int grp = s / 25, within = s % 25;
                    const int off = grp * GS + within;
                    const int bidx = tile * 125 + s;
                    const float bv = b3[bidx < N3 ? bidx : 0];
                    #pragma unroll
                    for (int i = 0; i < 4; i++) {
                        const int lrw = i * 16 + quad * 4;
                        #pragma unroll
                        for (int r2 = 0; r2 < 4; r2++)
                            eb[(lrw + r2) * RS + off] = acc[i][j][r2] + bv;
                    }
                }
            }
        }
        __syncthreads();
        #pragma unroll 1
        for (int q = t; q < 320; q += 256) {
            const int r  = q / 5;
            const int ds = q % 5;
            const int dim = tile * 5 + ds;
            if (dim < DIM) {
                // vectorized param fetch: 7 x ds_read_b128 (pad values unused)
                float pl[28];
                const floatx4* pv = (const floatx4*)(eb + r * RS + ds * GS);
                #pragma unroll
                for (int ii = 0; ii < 7; ii++) ((floatx4*)pl)[ii] = pv[ii];
                const int grow = bm + h * 64 + r;
                const float xv = x[(size_t)grow * DIM + dim];
                float y, l;
                spline_eval(pl, xv, y, l);
                out[(size_t)grow * DIM + dim] = y;
                atomicAdd(&ladacc[h * 64 + r], l);
            }
        }
    }
    __syncthreads();
    if (t < 128) atomicAdd(&lad[bm + t], ladacc[t]);
}

// ---------------------------------------------------------------- launch
extern "C" void kernel_launch(void* const* d_in, const int* in_sizes, int n_in,
                              void* d_out, int out_size, void* d_ws, size_t ws_size,
                              hipStream_t stream) {
    const float* x  = (const float*)d_in[0];
    const float* W1 = (const float*)d_in[1];
    const float* b1 = (const float*)d_in[2];
    const float* W2 = (const float*)d_in[3];
    const float* b2 = (const float*)d_in[4];
    const float* W3 = (const float*)d_in[5];
    const float* b3 = (const float*)d_in[6];
    const float* m1 = (const float*)d_in[7];
    const float* m3 = (const float*)d_in[9];

    // workspace: ~81 MB + small arrays
    char* ws = (char*)d_ws;
    const size_t OFF_W1B = 0;
    const size_t OFF_W2B = OFF_W1B + (size_t)HID * DIM * 2;
    const size_t OFF_W3P = OFF_W2B + (size_t)HID * HID * 2;
    const size_t OFF_XB  = OFF_W3P + (size_t)NP * HID * 2;
    const size_t OFF_H1B = OFF_XB  + (size_t)BATCH * DIM * 2;
    const size_t OFF_H2B = OFF_H1B + (size_t)BATCH * HID * 2;
    const size_t OFF_SML = OFF_H2B + (size_t)BATCH * HID * 2;

    __hip_bfloat16* w1p = (__hip_bfloat16*)(ws + OFF_W1B);
    __hip_bfloat16* w2p = (__hip_bfloat16*)(ws + OFF_W2B);
    __hip_bfloat16* w3p = (__hip_bfloat16*)(ws + OFF_W3P);
    __hip_bfloat16* xb  = (__hip_bfloat16*)(ws + OFF_XB);
    __hip_bfloat16* h1b = (__hip_bfloat16*)(ws + OFF_H1B);
    __hip_bfloat16* h2b = (__hip_bfloat16*)(ws + OFF_H2B);

    float* b1p   = (float*)(ws + OFF_SML);
    float* b2p   = b1p + HID;
    int*   h1i   = (int*)(b2p + HID);
    int*   h2i   = h1i + HID;
    int*   perm1 = h2i + HID;
    int*   perm2 = perm1 + HID;
    int*   h1sv  = perm2 + HID;
    int*   h2sv  = h1sv + HID;
    int*   klim1 = h2sv + HID;
    int*   klim2 = klim1 + 8;
    int*   klim3 = klim2 + 8;

    float* out_p = (float*)d_out;
    float* lad_p = out_p + (size_t)BATCH * DIM;

    // prep: parallel h1/h2/x-cast, then sort, then weight permutes
    hsum_kernel<<<2 * HID + (BATCH * DIM) / 1024, 128, 0, stream>>>(
        m1, m3, x, xb, lad_p, h1i, h2i);
    sort_kernel<<<1, 1024, 0, stream>>>(h1i, h2i, perm1, perm2, h1sv, h2sv,
                                        klim1, klim2, klim3);
    wperm_kernel<<<512 + HID + NP, 256, 0, stream>>>(
        W1, b1, W2, b2, W3, perm1, perm2, h1sv, h2sv,
        w1p, b1p, w2p, b2p, w3p);

    // GEMMs (per-tile K bounds from sorted-mask prefixes)
    gemm_bt_kernel<<<dim3(HID / 128, BATCH / 128), 256, 0, stream>>>(
        (const unsigned short*)xb, (const unsigned short*)w1p, b1p, klim1, h1b,
        BATCH, HID, DIM);
    gemm_bt_kernel<<<dim3(HID / 128, BATCH / 128), 256, 0, stream>>>(
        (const unsigned short*)h1b, (const unsigned short*)w2p, b2p, klim2, h2b,
        BATCH, HID, HID);
    gemm3_spline_kernel<<<dim3(NP / 128, BATCH / 128), 256, 0, stream>>>(
        (const unsigned short*)h2b, (const unsigned short*)w3p, b3, klim3, x,
        out_p, lad_p, BATCH);
}